// Round 4
// baseline (368.636 us; speedup 1.0000x reference)
//
#include <hip/hip_runtime.h>
#include <hip/hip_bf16.h>

typedef unsigned short u16;
typedef __attribute__((ext_vector_type(8))) short s16x8;
typedef __attribute__((ext_vector_type(8))) unsigned short u16x8;
typedef __attribute__((ext_vector_type(4))) float f32x4;

#define SEQ 2048
#define KEXP 0.18033688011112042f  /* 0.125 * log2(e) */

__device__ __forceinline__ float bf2f(u16 x) {
  union { unsigned u; float f; } c; c.u = ((unsigned)x) << 16; return c.f;
}
// hardware bf16 convert (v_cvt_pk_bf16_f32 on gfx950)
__device__ __forceinline__ u16 f2bf(float f) {
  __hip_bfloat16 h = __float2bfloat16(f);
  return __builtin_bit_cast(u16, h);
}
__device__ __forceinline__ unsigned pack2(float a, float b) {
  return (unsigned)f2bf(a) | ((unsigned)f2bf(b) << 16);
}

// ---------------- fp32 -> bf16 flat convert ----------------
__global__ __launch_bounds__(256) void k_cvt(const float* __restrict__ src,
                                             u16* __restrict__ dst, int n4) {
  int i = blockIdx.x * 256 + threadIdx.x;
  if (i >= n4) return;
  float4 v = ((const float4*)src)[i];
  ((ushort4*)dst)[i] = make_ushort4(f2bf(v.x), f2bf(v.y), f2bf(v.z), f2bf(v.w));
}

// ---------------- fp32 [R][C] -> bf16 [C][R] transpose-convert ----------------
__global__ __launch_bounds__(256) void k_tcvt(const float* __restrict__ src,
                                              u16* __restrict__ dst, int R, int C) {
  __shared__ u16 T[64][72];
  int r0 = blockIdx.y * 64, c0 = blockIdx.x * 64;
  int tid = threadIdx.x;
#pragma unroll
  for (int p = 0; p < 4; ++p) {
    int f = p * 256 + tid;            // float4 id within 64x64 tile
    int r = f >> 4, cc = (f & 15) * 4;
    float4 v = *(const float4*)(src + (size_t)(r0 + r) * C + c0 + cc);
    T[r][cc + 0] = f2bf(v.x); T[r][cc + 1] = f2bf(v.y);
    T[r][cc + 2] = f2bf(v.z); T[r][cc + 3] = f2bf(v.w);
  }
  __syncthreads();
#pragma unroll
  for (int p = 0; p < 2; ++p) {
    int f = p * 256 + tid;            // u16x8 chunk id
    int c = f >> 3, rr = (f & 7) * 8;
    u16x8 v;
#pragma unroll
    for (int e = 0; e < 8; ++e) v[e] = T[rr + e][c];
    *(u16x8*)(dst + (size_t)(c0 + c) * R + r0 + rr) = v;
  }
}

// ---------------- C[M,N] = A[M,K] @ Bt[N,K]^T  (bf16 in, bf16 or f32+res out) ----
template <int RES>
__global__ __launch_bounds__(256) void k_gemm_bt(const u16* __restrict__ A,
                                                 const u16* __restrict__ Bt,
                                                 u16* __restrict__ Cb,
                                                 float* __restrict__ Cf,
                                                 const float* __restrict__ res,
                                                 int M, int N, int K) {
  __shared__ u16 As[128 * 72];
  __shared__ u16 Bs[128 * 72];
  const int tid = threadIdx.x;
  const int l = tid & 63, wv = tid >> 6;
  const int g = l >> 4, c16 = l & 15;
  const int m0 = blockIdx.x * 128, n0 = blockIdx.y * 128;
  const int wr = (wv >> 1) * 64, wc = (wv & 1) * 64;
  f32x4 acc[4][4] = {};
  for (int k0 = 0; k0 < K; k0 += 64) {
    __syncthreads();
    // 128 rows x 64 k = 1024 16B-chunks per matrix; 256 threads -> 4 iters
#pragma unroll
    for (int p = 0; p < 4; ++p) {
      int f = p * 256 + tid;
      int row = f >> 3, kb = (f & 7) * 8;
      u16x8 va = *(const u16x8*)(A + (size_t)(m0 + row) * K + k0 + kb);
      u16x8 vb = *(const u16x8*)(Bt + (size_t)(n0 + row) * K + k0 + kb);
      *(u16x8*)&As[row * 72 + kb] = va;
      *(u16x8*)&Bs[row * 72 + kb] = vb;
    }
    __syncthreads();
#pragma unroll
    for (int ks = 0; ks < 2; ++ks) {
      s16x8 af[4], bf[4];
#pragma unroll
      for (int fr = 0; fr < 4; ++fr)
        af[fr] = *(const s16x8*)&As[(wr + fr * 16 + c16) * 72 + ks * 32 + g * 8];
#pragma unroll
      for (int fc = 0; fc < 4; ++fc)
        bf[fc] = *(const s16x8*)&Bs[(wc + fc * 16 + c16) * 72 + ks * 32 + g * 8];
#pragma unroll
      for (int fr = 0; fr < 4; ++fr)
#pragma unroll
        for (int fc = 0; fc < 4; ++fc)
          acc[fr][fc] = __builtin_amdgcn_mfma_f32_16x16x32_bf16(af[fr], bf[fc],
                                                                acc[fr][fc], 0, 0, 0);
    }
  }
#pragma unroll
  for (int fr = 0; fr < 4; ++fr)
#pragma unroll
    for (int fc = 0; fc < 4; ++fc)
#pragma unroll
      for (int reg = 0; reg < 4; ++reg) {
        int row = m0 + wr + fr * 16 + g * 4 + reg;
        int col = n0 + wc + fc * 16 + c16;
        float v = acc[fr][fc][reg];
        if (RES) Cf[(size_t)row * N + col] = v + res[(size_t)row * N + col];
        else     Cb[(size_t)row * N + col] = f2bf(v);
      }
}

// ---------------- build V^T [b][n][d][j] from qkv ----------------
__global__ __launch_bounds__(256) void k_vt(const u16* __restrict__ qkv,
                                            u16* __restrict__ vT) {
  __shared__ u16 T[64][72];
  const int tid = threadIdx.x;
  const int j0 = blockIdx.x * 64;
  const int n = blockIdx.y & 15, b = blockIdx.y >> 4;
#pragma unroll
  for (int p = 0; p < 2; ++p) {
    int f = p * 256 + tid;
    int r = f >> 3, cc = (f & 7) * 8;
    *(u16x8*)&T[r][cc] =
        *(const u16x8*)(qkv + ((size_t)((j0 + r) * 2 + b)) * 3072 + 2048 + n * 64 + cc);
  }
  __syncthreads();
#pragma unroll
  for (int p = 0; p < 2; ++p) {
    int f = p * 256 + tid;
    int d = f >> 3, jc = (f & 7) * 8;
    u16x8 v;
#pragma unroll
    for (int e = 0; e < 8; ++e) v[e] = T[jc + e][d];
    *(u16x8*)(vT + ((size_t)((b * 16 + n) * 64 + d)) * 2048 + j0 + jc) = v;
  }
}

// ---------------- fused rel-attention (flash-style) ----------------
// Grid: 1024 flat blocks. LDS ~35.3KB -> 4 blocks/CU (exactly 1024/256CU, no tail).
__global__ __launch_bounds__(256, 4) void k_attn(const u16* __restrict__ qkv,
                                                 const u16* __restrict__ rk,
                                                 const u16* __restrict__ vT,
                                                 const float* __restrict__ rwb,
                                                 const float* __restrict__ rrb,
                                                 u16* __restrict__ av) {
  __shared__ u16 KtPt[64][72];  // K tile [j][d] during AC; P (probs) during PV
  __shared__ u16 Vt[64][72];    // V^T tile [d][j]
  __shared__ u16 St[128][66];   // shifted band S^T[w][ii] = QR[ii+delta(w)][w]

  const int tid = threadIdx.x;
  const int l = tid & 63, wv = tid >> 6;
  const int g = l >> 4, c16 = l & 15;
  // XCD-aware swizzle: 4 consecutive bn per XCD -> K/V/rk L2-resident
  const int s = blockIdx.x;
  const int y = (s & 7) + 8 * (s >> 8);  // bn
  const int x = (s >> 3) & 31;           // i-tile
  const int i0 = x * 64;
  const int n = y & 15, b = y >> 4;
  const f32x4 zero4 = {0.f, 0.f, 0.f, 0.f};
  const s16x8 zero8 = {0, 0, 0, 0, 0, 0, 0, 0};

  // ---- register-staged Q fragments (loop-invariant) ----
  // qw: AC A-frag (Q + r_w_bias), wave wv owns rows wv*16..+15
  s16x8 qw[2];
  {
    int i = i0 + wv * 16 + c16;
    const u16* src = qkv + ((size_t)(i * 2 + b)) * 3072 + n * 64;
#pragma unroll
    for (int ks = 0; ks < 2; ++ks) {
      int d0 = ks * 32 + g * 8;
      u16x8 raw = *(const u16x8*)(src + d0);
      u16x8 wq;
#pragma unroll
      for (int e = 0; e < 8; ++e)
        wq[e] = f2bf(bf2f(raw[e]) + rwb[n * 64 + d0 + e]);
      qw[ks] = __builtin_bit_cast(s16x8, wq);
    }
  }
  // qr_a: QR producer A-frags (Q + r_r_bias), rows rg*16+c16 (block-local 0..63)
  s16x8 qr_a[4][2];
#pragma unroll
  for (int rg = 0; rg < 4; ++rg) {
    int i = i0 + rg * 16 + c16;
    const u16* src = qkv + ((size_t)(i * 2 + b)) * 3072 + n * 64;
#pragma unroll
    for (int ks = 0; ks < 2; ++ks) {
      int d0 = ks * 32 + g * 8;
      u16x8 raw = *(const u16x8*)(src + d0);
      u16x8 wq;
#pragma unroll
      for (int e = 0; e < 8; ++e)
        wq[e] = f2bf(bf2f(raw[e]) + rrb[n * 64 + d0 + e]);
      qr_a[rg][ks] = __builtin_bit_cast(s16x8, wq);
    }
  }
  // q64: band row 64 (Q'[i0+64]) in lane c16==0 only; zeros elsewhere / OOB
  s16x8 q64[2];
  {
    bool valid = (c16 == 0) && (i0 + 64 < SEQ);
#pragma unroll
    for (int ks = 0; ks < 2; ++ks) q64[ks] = zero8;
    if (valid) {
      const u16* src = qkv + ((size_t)((i0 + 64) * 2 + b)) * 3072 + n * 64;
#pragma unroll
      for (int ks = 0; ks < 2; ++ks) {
        int d0 = ks * 32 + g * 8;
        u16x8 raw = *(const u16x8*)(src + d0);
        u16x8 wq;
#pragma unroll
        for (int e = 0; e < 8; ++e)
          wq[e] = f2bf(bf2f(raw[e]) + rrb[n * 64 + d0 + e]);
        q64[ks] = __builtin_bit_cast(s16x8, wq);
      }
    }
  }

  float m_prev[4], l_sum[4];
  f32x4 o_acc[4];
#pragma unroll
  for (int r = 0; r < 4; ++r) { m_prev[r] = -1e30f; l_sum[r] = 0.f; o_acc[r] = zero4; }

  for (int kt = 0; kt < 32; ++kt) {
    const int j0 = kt * 64;
    const int thr = 64 + i0 - j0;      // delta(w) = (w >= thr); thr % 16 == 0
    const int cfthr = thr >> 4;
    __syncthreads();

    // direct-load QR B-fragments from global rk (L2-hot), issued early
    s16x8 rbf[2][2];
#pragma unroll
    for (int c2 = 0; c2 < 2; ++c2) {
      int w = (wv * 2 + c2) * 16 + c16;
      int u = j0 - i0 - 63 + w;
      int c = (u <= 0) ? (u + (SEQ - 1)) : (u - 2);
      const u16* p = rk + (size_t)(c < 0 ? 0 : c) * 1024 + n * 64;
      rbf[c2][0] = *(const s16x8*)(p + g * 8);
      rbf[c2][1] = *(const s16x8*)(p + 32 + g * 8);
      if (c < 0) { rbf[c2][0] = zero8; rbf[c2][1] = zero8; }
    }

    // stage K tile into KtPt
#pragma unroll
    for (int p = 0; p < 2; ++p) {
      int f = p * 256 + tid;
      int r = f >> 3, cc = (f & 7) * 8;
      *(u16x8*)&KtPt[r][cc] =
          *(const u16x8*)(qkv + ((size_t)((j0 + r) * 2 + b)) * 3072 + 1024 + n * 64 + cc);
    }
    // stage V^T tile
#pragma unroll
    for (int p = 0; p < 2; ++p) {
      int f = p * 256 + tid;
      int r = f >> 3, cc = (f & 7) * 8;
      *(u16x8*)&Vt[r][cc] =
          *(const u16x8*)(vT + ((size_t)((b * 16 + n) * 64 + r)) * 2048 + j0 + cc);
    }
    __syncthreads();

    // AC = (Q+rw) @ K^T
    f32x4 sc[4];
#pragma unroll
    for (int fj = 0; fj < 4; ++fj) sc[fj] = zero4;
#pragma unroll
    for (int ks = 0; ks < 2; ++ks)
#pragma unroll
      for (int fj = 0; fj < 4; ++fj) {
        s16x8 bf = *(const s16x8*)&KtPt[fj * 16 + c16][ks * 32 + g * 8];
        sc[fj] = __builtin_amdgcn_mfma_f32_16x16x32_bf16(qw[ks], bf, sc[fj], 0, 0, 0);
      }

    // QR band producer, shift baked in: St[w][r - delta] (delta wave-uniform)
#pragma unroll
    for (int c2 = 0; c2 < 2; ++c2) {
      const int cfe = wv * 2 + c2;
      const bool du = (cfe >= cfthr);   // wave-uniform delta for this w-column
      const int w = cfe * 16 + c16;
#pragma unroll
      for (int rg = 0; rg < 4; ++rg) {
        f32x4 qr = zero4;
        qr = __builtin_amdgcn_mfma_f32_16x16x32_bf16(qr_a[rg][0], rbf[c2][0], qr, 0, 0, 0);
        qr = __builtin_amdgcn_mfma_f32_16x16x32_bf16(qr_a[rg][1], rbf[c2][1], qr, 0, 0, 0);
        const int B = rg * 16 + g * 4;  // output row base (even -> b32-aligned)
        if (!du) {
          *(unsigned*)&St[w][B] = pack2(qr[0], qr[1]);
          *(unsigned*)&St[w][B + 2] = pack2(qr[2], qr[3]);
        } else if (B == 0) {
          // rows r=0..3 -> r'=-1..2: drop r'=-1
          *(unsigned*)&St[w][0] = pack2(qr[1], qr[2]);
          St[w][2] = f2bf(qr[3]);
        } else {
          St[w][B - 1] = f2bf(qr[0]);
          *(unsigned*)&St[w][B] = pack2(qr[1], qr[2]);
          St[w][B + 2] = f2bf(qr[3]);
        }
      }
      // band row 64 -> St[w][63] (only when delta=1)
      if (du) {
        f32x4 q64o = zero4;
        q64o = __builtin_amdgcn_mfma_f32_16x16x32_bf16(q64[0], rbf[c2][0], q64o, 0, 0, 0);
        q64o = __builtin_amdgcn_mfma_f32_16x16x32_bf16(q64[1], rbf[c2][1], q64o, 0, 0, 0);
        if (g == 0) St[w][63] = f2bf(q64o[0]);
      }
    }
    __syncthreads();

    // gather BD: one base pointer + compile-time immediate offsets
    {
      const char* Sbase = (const char*)&St[0][0] +
                          ((c16 + 63) * 132 - (wv * 16 + g * 4) * 130 - 390);
#pragma unroll
      for (int fj = 0; fj < 4; ++fj)
#pragma unroll
        for (int reg = 0; reg < 4; ++reg)
          sc[fj][reg] += bf2f(*(const u16*)(Sbase + fj * 2112 + (3 - reg) * 130));
    }

    // online softmax
    float mt[4];
#pragma unroll
    for (int reg = 0; reg < 4; ++reg)
      mt[reg] = fmaxf(fmaxf(sc[0][reg], sc[1][reg]), fmaxf(sc[2][reg], sc[3][reg]));
#pragma unroll
    for (int off = 1; off < 16; off <<= 1)
#pragma unroll
      for (int reg = 0; reg < 4; ++reg)
        mt[reg] = fmaxf(mt[reg], __shfl_xor(mt[reg], off, 16));
    float al[4], rs[4];
#pragma unroll
    for (int reg = 0; reg < 4; ++reg) {
      float mn = fmaxf(m_prev[reg], mt[reg]);
      al[reg] = __builtin_amdgcn_exp2f((m_prev[reg] - mn) * KEXP);
      m_prev[reg] = mn;
      rs[reg] = 0.f;
    }
    // P tile into KtPt (Kt fully consumed before the post-QR barrier)
#pragma unroll
    for (int fj = 0; fj < 4; ++fj)
#pragma unroll
      for (int reg = 0; reg < 4; ++reg) {
        float p = __builtin_amdgcn_exp2f((sc[fj][reg] - m_prev[reg]) * KEXP);
        rs[reg] += p;
        KtPt[wv * 16 + g * 4 + reg][fj * 16 + c16] = f2bf(p);
      }
#pragma unroll
    for (int off = 1; off < 16; off <<= 1)
#pragma unroll
      for (int reg = 0; reg < 4; ++reg)
        rs[reg] += __shfl_xor(rs[reg], off, 16);
#pragma unroll
    for (int reg = 0; reg < 4; ++reg)
      l_sum[reg] = l_sum[reg] * al[reg] + rs[reg];
#pragma unroll
    for (int fd = 0; fd < 4; ++fd)
#pragma unroll
      for (int reg = 0; reg < 4; ++reg)
        o_acc[fd][reg] *= al[reg];

    // PV: O += P @ V   (P rows are same-wave; compiler inserts lgkmcnt)
#pragma unroll
    for (int ks = 0; ks < 2; ++ks) {
      s16x8 pa = *(const s16x8*)&KtPt[wv * 16 + c16][ks * 32 + g * 8];
#pragma unroll
      for (int fd = 0; fd < 4; ++fd) {
        s16x8 vb = *(const s16x8*)&Vt[fd * 16 + c16][ks * 32 + g * 8];
        o_acc[fd] = __builtin_amdgcn_mfma_f32_16x16x32_bf16(pa, vb, o_acc[fd], 0, 0, 0);
      }
    }
  }

#pragma unroll
  for (int reg = 0; reg < 4; ++reg) {
    float inv = 1.0f / l_sum[reg];
    int i = i0 + wv * 16 + g * 4 + reg;
    u16* dst = av + ((size_t)(i * 2 + b)) * 1024 + n * 64;
#pragma unroll
    for (int fd = 0; fd < 4; ++fd)
      dst[fd * 16 + c16] = f2bf(o_acc[fd][reg] * inv);
  }
}

// ---------------- LayerNorm over rows of tmp (= attn_out + h) ----------------
__global__ __launch_bounds__(256) void k_ln(const float* __restrict__ tmp,
                                            const float* __restrict__ gamma,
                                            const float* __restrict__ beta,
                                            float* __restrict__ out) {
  __shared__ float r1[4], r2[4];
  const int row = blockIdx.x, tid = threadIdx.x;
  const float* x = tmp + (size_t)row * 1024;
  float4 v = *(const float4*)(x + tid * 4);
  float s1 = v.x + v.y + v.z + v.w;
  float s2 = v.x * v.x + v.y * v.y + v.z * v.z + v.w * v.w;
#pragma unroll
  for (int off = 1; off < 64; off <<= 1) {
    s1 += __shfl_xor(s1, off, 64);
    s2 += __shfl_xor(s2, off, 64);
  }
  if ((tid & 63) == 0) { r1[tid >> 6] = s1; r2[tid >> 6] = s2; }
  __syncthreads();
  s1 = r1[0] + r1[1] + r1[2] + r1[3];
  s2 = r2[0] + r2[1] + r2[2] + r2[3];
  float mu = s1 * (1.f / 1024.f);
  float var = s2 * (1.f / 1024.f) - mu * mu;
  float rstd = rsqrtf(var + 1e-6f);
  float4 gm = *(const float4*)(gamma + tid * 4);
  float4 bt = *(const float4*)(beta + tid * 4);
  float4 o;
  o.x = (v.x - mu) * rstd * gm.x + bt.x;
  o.y = (v.y - mu) * rstd * gm.y + bt.y;
  o.z = (v.z - mu) * rstd * gm.z + bt.z;
  o.w = (v.w - mu) * rstd * gm.w + bt.w;
  *(float4*)(out + (size_t)row * 1024 + tid * 4) = o;
}

// ---------------- launch ----------------
extern "C" void kernel_launch(void* const* d_in, const int* in_sizes, int n_in,
                              void* d_out, int out_size, void* d_ws, size_t ws_size,
                              hipStream_t stream) {
  const float* h    = (const float*)d_in[0];
  const float* r    = (const float*)d_in[1];
  const float* rwb  = (const float*)d_in[2];
  const float* rrb  = (const float*)d_in[3];
  const float* Wqkv = (const float*)d_in[4];
  const float* Wr   = (const float*)d_in[5];
  const float* Wo   = (const float*)d_in[6];
  const float* gam  = (const float*)d_in[7];
  const float* bet  = (const float*)d_in[8];
  float* out = (float*)d_out;

  u16* hb     = (u16*)d_ws;                          // 4096*1024
  u16* Wqkv_t = hb + (size_t)4096 * 1024;            // 3072*1024
  u16* Wr_t   = Wqkv_t + (size_t)3072 * 1024;        // 1024*1024
  u16* Wo_t   = Wr_t + (size_t)1024 * 1024;          // 1024*1024
  u16* rb     = Wo_t + (size_t)1024 * 1024;          // 2048*1024
  u16* qkv    = rb + (size_t)2048 * 1024;            // 4096*3072
  u16* rk     = qkv + (size_t)4096 * 3072;           // 2048*1024
  u16* vT     = rk + (size_t)2048 * 1024;            // 2*16*64*2048
  u16* av     = vT + (size_t)2 * 16 * 64 * 2048;     // 4096*1024
  float* tmp  = (float*)(av + (size_t)4096 * 1024);  // 4096*1024 f32

  k_cvt<<<4096, 256, 0, stream>>>(h, hb, 4096 * 1024 / 4);
  k_cvt<<<2048, 256, 0, stream>>>(r, rb, 2048 * 1024 / 4);
  k_tcvt<<<dim3(48, 16), 256, 0, stream>>>(Wqkv, Wqkv_t, 1024, 3072);
  k_tcvt<<<dim3(16, 16), 256, 0, stream>>>(Wr, Wr_t, 1024, 1024);
  k_tcvt<<<dim3(16, 16), 256, 0, stream>>>(Wo, Wo_t, 1024, 1024);
  k_gemm_bt<0><<<dim3(32, 24), 256, 0, stream>>>(hb, Wqkv_t, qkv, nullptr, nullptr,
                                                 4096, 3072, 1024);
  k_gemm_bt<0><<<dim3(16, 8), 256, 0, stream>>>(rb, Wr_t, rk, nullptr, nullptr,
                                                2048, 1024, 1024);
  k_vt<<<dim3(32, 32), 256, 0, stream>>>(qkv, vT);
  k_attn<<<1024, 256, 0, stream>>>(qkv, rk, vT, rwb, rrb, av);
  k_gemm_bt<1><<<dim3(32, 8), 256, 0, stream>>>(av, Wo_t, nullptr, tmp, h,
                                                4096, 1024, 1024);
  k_ln<<<4096, 256, 0, stream>>>(tmp, gam, bet, out);
}

// Round 5
// 357.419 us; speedup vs baseline: 1.0314x; 1.0314x over previous
//
#include <hip/hip_runtime.h>
#include <hip/hip_bf16.h>

typedef unsigned short u16;
typedef __attribute__((ext_vector_type(8))) short s16x8;
typedef __attribute__((ext_vector_type(8))) unsigned short u16x8;
typedef __attribute__((ext_vector_type(4))) float f32x4;

#define SEQ 2048
#define KEXP 0.18033688011112042f  /* 0.125 * log2(e) */

__device__ __forceinline__ float bf2f(u16 x) {
  union { unsigned u; float f; } c; c.u = ((unsigned)x) << 16; return c.f;
}
// hardware bf16 convert (v_cvt_pk_bf16_f32 on gfx950)
__device__ __forceinline__ u16 f2bf(float f) {
  __hip_bfloat16 h = __float2bfloat16(f);
  return __builtin_bit_cast(u16, h);
}
__device__ __forceinline__ unsigned pack2(float a, float b) {
  return (unsigned)f2bf(a) | ((unsigned)f2bf(b) << 16);
}

// ---------------- fp32 -> bf16 flat convert ----------------
__global__ __launch_bounds__(256) void k_cvt(const float* __restrict__ src,
                                             u16* __restrict__ dst, int n4) {
  int i = blockIdx.x * 256 + threadIdx.x;
  if (i >= n4) return;
  float4 v = ((const float4*)src)[i];
  ((ushort4*)dst)[i] = make_ushort4(f2bf(v.x), f2bf(v.y), f2bf(v.z), f2bf(v.w));
}

// ---------------- fp32 [R][C] -> bf16 [C][R] transpose-convert ----------------
__global__ __launch_bounds__(256) void k_tcvt(const float* __restrict__ src,
                                              u16* __restrict__ dst, int R, int C) {
  __shared__ u16 T[64][72];
  int r0 = blockIdx.y * 64, c0 = blockIdx.x * 64;
  int tid = threadIdx.x;
#pragma unroll
  for (int p = 0; p < 4; ++p) {
    int f = p * 256 + tid;            // float4 id within 64x64 tile
    int r = f >> 4, cc = (f & 15) * 4;
    float4 v = *(const float4*)(src + (size_t)(r0 + r) * C + c0 + cc);
    T[r][cc + 0] = f2bf(v.x); T[r][cc + 1] = f2bf(v.y);
    T[r][cc + 2] = f2bf(v.z); T[r][cc + 3] = f2bf(v.w);
  }
  __syncthreads();
#pragma unroll
  for (int p = 0; p < 2; ++p) {
    int f = p * 256 + tid;            // u16x8 chunk id
    int c = f >> 3, rr = (f & 7) * 8;
    u16x8 v;
#pragma unroll
    for (int e = 0; e < 8; ++e) v[e] = T[rr + e][c];
    *(u16x8*)(dst + (size_t)(c0 + c) * R + r0 + rr) = v;
  }
}

// ---------------- C[M,N] = A[M,K] @ Bt[N,K]^T  (bf16 in, bf16 or f32+res out) ----
template <int RES>
__global__ __launch_bounds__(256) void k_gemm_bt(const u16* __restrict__ A,
                                                 const u16* __restrict__ Bt,
                                                 u16* __restrict__ Cb,
                                                 float* __restrict__ Cf,
                                                 const float* __restrict__ res,
                                                 int M, int N, int K) {
  __shared__ u16 As[128 * 72];
  __shared__ u16 Bs[128 * 72];
  const int tid = threadIdx.x;
  const int l = tid & 63, wv = tid >> 6;
  const int g = l >> 4, c16 = l & 15;
  const int m0 = blockIdx.x * 128, n0 = blockIdx.y * 128;
  const int wr = (wv >> 1) * 64, wc = (wv & 1) * 64;
  f32x4 acc[4][4] = {};
  for (int k0 = 0; k0 < K; k0 += 64) {
    __syncthreads();
    // 128 rows x 64 k = 1024 16B-chunks per matrix; 256 threads -> 4 iters
#pragma unroll
    for (int p = 0; p < 4; ++p) {
      int f = p * 256 + tid;
      int row = f >> 3, kb = (f & 7) * 8;
      u16x8 va = *(const u16x8*)(A + (size_t)(m0 + row) * K + k0 + kb);
      u16x8 vb = *(const u16x8*)(Bt + (size_t)(n0 + row) * K + k0 + kb);
      *(u16x8*)&As[row * 72 + kb] = va;
      *(u16x8*)&Bs[row * 72 + kb] = vb;
    }
    __syncthreads();
#pragma unroll
    for (int ks = 0; ks < 2; ++ks) {
      s16x8 af[4], bf[4];
#pragma unroll
      for (int fr = 0; fr < 4; ++fr)
        af[fr] = *(const s16x8*)&As[(wr + fr * 16 + c16) * 72 + ks * 32 + g * 8];
#pragma unroll
      for (int fc = 0; fc < 4; ++fc)
        bf[fc] = *(const s16x8*)&Bs[(wc + fc * 16 + c16) * 72 + ks * 32 + g * 8];
#pragma unroll
      for (int fr = 0; fr < 4; ++fr)
#pragma unroll
        for (int fc = 0; fc < 4; ++fc)
          acc[fr][fc] = __builtin_amdgcn_mfma_f32_16x16x32_bf16(af[fr], bf[fc],
                                                                acc[fr][fc], 0, 0, 0);
    }
  }
#pragma unroll
  for (int fr = 0; fr < 4; ++fr)
#pragma unroll
    for (int fc = 0; fc < 4; ++fc)
#pragma unroll
      for (int reg = 0; reg < 4; ++reg) {
        int row = m0 + wr + fr * 16 + g * 4 + reg;
        int col = n0 + wc + fc * 16 + c16;
        float v = acc[fr][fc][reg];
        if (RES) Cf[(size_t)row * N + col] = v + res[(size_t)row * N + col];
        else     Cb[(size_t)row * N + col] = f2bf(v);
      }
}

// ---------------- build V^T [b][n][d][j] from qkv ----------------
__global__ __launch_bounds__(256) void k_vt(const u16* __restrict__ qkv,
                                            u16* __restrict__ vT) {
  __shared__ u16 T[64][72];
  const int tid = threadIdx.x;
  const int j0 = blockIdx.x * 64;
  const int n = blockIdx.y & 15, b = blockIdx.y >> 4;
#pragma unroll
  for (int p = 0; p < 2; ++p) {
    int f = p * 256 + tid;
    int r = f >> 3, cc = (f & 7) * 8;
    *(u16x8*)&T[r][cc] =
        *(const u16x8*)(qkv + ((size_t)((j0 + r) * 2 + b)) * 3072 + 2048 + n * 64 + cc);
  }
  __syncthreads();
#pragma unroll
  for (int p = 0; p < 2; ++p) {
    int f = p * 256 + tid;
    int d = f >> 3, jc = (f & 7) * 8;
    u16x8 v;
#pragma unroll
    for (int e = 0; e < 8; ++e) v[e] = T[jc + e][d];
    *(u16x8*)(vT + ((size_t)((b * 16 + n) * 64 + d)) * 2048 + j0 + jc) = v;
  }
}

// ---------------- fused rel-attention (flash-style) ----------------
// Grid: 1024 flat blocks. LDS ~35.3KB -> 4 blocks/CU if VGPR<=128.
// NOTE: no min-waves arg in launch_bounds — (256,4) made the allocator snap to
// 64 VGPR and spill ~50 regs to scratch (R4: WRITE_SIZE 4x, dur +20%).
__global__ __launch_bounds__(256) void k_attn(const u16* __restrict__ qkv,
                                              const u16* __restrict__ rk,
                                              const u16* __restrict__ vT,
                                              const float* __restrict__ rwb,
                                              const float* __restrict__ rrb,
                                              u16* __restrict__ av) {
  __shared__ u16 KtPt[64][72];  // K tile [j][d] during AC; P (probs) during PV
  __shared__ u16 Vt[64][72];    // V^T tile [d][j]
  __shared__ u16 St[128][66];   // shifted band S^T[w][ii] = QR[ii+delta(w)][w]

  const int tid = threadIdx.x;
  const int l = tid & 63, wv = tid >> 6;
  const int g = l >> 4, c16 = l & 15;
  // XCD-aware swizzle: 4 consecutive bn per XCD -> K/V/rk L2-resident
  const int s = blockIdx.x;
  const int y = (s & 7) + 8 * (s >> 8);  // bn
  const int x = (s >> 3) & 31;           // i-tile
  const int i0 = x * 64;
  const int n = y & 15, b = y >> 4;
  const f32x4 zero4 = {0.f, 0.f, 0.f, 0.f};
  const s16x8 zero8 = {0, 0, 0, 0, 0, 0, 0, 0};

  // ---- register-staged Q fragments (loop-invariant) ----
  // qw: AC A-frag (Q + r_w_bias), wave wv owns rows wv*16..+15
  s16x8 qw[2];
  {
    int i = i0 + wv * 16 + c16;
    const u16* src = qkv + ((size_t)(i * 2 + b)) * 3072 + n * 64;
#pragma unroll
    for (int ks = 0; ks < 2; ++ks) {
      int d0 = ks * 32 + g * 8;
      u16x8 raw = *(const u16x8*)(src + d0);
      u16x8 wq;
#pragma unroll
      for (int e = 0; e < 8; ++e)
        wq[e] = f2bf(bf2f(raw[e]) + rwb[n * 64 + d0 + e]);
      qw[ks] = __builtin_bit_cast(s16x8, wq);
    }
  }
  // qr_a: QR producer A-frags (Q + r_r_bias), rows rg*16+c16 (block-local 0..63)
  s16x8 qr_a[4][2];
#pragma unroll
  for (int rg = 0; rg < 4; ++rg) {
    int i = i0 + rg * 16 + c16;
    const u16* src = qkv + ((size_t)(i * 2 + b)) * 3072 + n * 64;
#pragma unroll
    for (int ks = 0; ks < 2; ++ks) {
      int d0 = ks * 32 + g * 8;
      u16x8 raw = *(const u16x8*)(src + d0);
      u16x8 wq;
#pragma unroll
      for (int e = 0; e < 8; ++e)
        wq[e] = f2bf(bf2f(raw[e]) + rrb[n * 64 + d0 + e]);
      qr_a[rg][ks] = __builtin_bit_cast(s16x8, wq);
    }
  }
  // q64: band row 64 (Q'[i0+64]) in lane c16==0 only; zeros elsewhere / OOB
  s16x8 q64[2];
  {
    bool valid = (c16 == 0) && (i0 + 64 < SEQ);
#pragma unroll
    for (int ks = 0; ks < 2; ++ks) q64[ks] = zero8;
    if (valid) {
      const u16* src = qkv + ((size_t)((i0 + 64) * 2 + b)) * 3072 + n * 64;
#pragma unroll
      for (int ks = 0; ks < 2; ++ks) {
        int d0 = ks * 32 + g * 8;
        u16x8 raw = *(const u16x8*)(src + d0);
        u16x8 wq;
#pragma unroll
        for (int e = 0; e < 8; ++e)
          wq[e] = f2bf(bf2f(raw[e]) + rrb[n * 64 + d0 + e]);
        q64[ks] = __builtin_bit_cast(s16x8, wq);
      }
    }
  }

  float m_prev[4], l_sum[4];
  f32x4 o_acc[4];
#pragma unroll
  for (int r = 0; r < 4; ++r) { m_prev[r] = -1e30f; l_sum[r] = 0.f; o_acc[r] = zero4; }

  for (int kt = 0; kt < 32; ++kt) {
    const int j0 = kt * 64;
    const int thr = 64 + i0 - j0;      // delta(w) = (w >= thr); thr % 16 == 0
    const int cfthr = thr >> 4;
    __syncthreads();

    // direct-load QR B-fragments from global rk (L2-hot), issued early
    s16x8 rbf[2][2];
#pragma unroll
    for (int c2 = 0; c2 < 2; ++c2) {
      int w = (wv * 2 + c2) * 16 + c16;
      int u = j0 - i0 - 63 + w;
      int c = (u <= 0) ? (u + (SEQ - 1)) : (u - 2);
      const u16* p = rk + (size_t)(c < 0 ? 0 : c) * 1024 + n * 64;
      rbf[c2][0] = *(const s16x8*)(p + g * 8);
      rbf[c2][1] = *(const s16x8*)(p + 32 + g * 8);
      if (c < 0) { rbf[c2][0] = zero8; rbf[c2][1] = zero8; }
    }

    // stage K tile into KtPt
#pragma unroll
    for (int p = 0; p < 2; ++p) {
      int f = p * 256 + tid;
      int r = f >> 3, cc = (f & 7) * 8;
      *(u16x8*)&KtPt[r][cc] =
          *(const u16x8*)(qkv + ((size_t)((j0 + r) * 2 + b)) * 3072 + 1024 + n * 64 + cc);
    }
    // stage V^T tile
#pragma unroll
    for (int p = 0; p < 2; ++p) {
      int f = p * 256 + tid;
      int r = f >> 3, cc = (f & 7) * 8;
      *(u16x8*)&Vt[r][cc] =
          *(const u16x8*)(vT + ((size_t)((b * 16 + n) * 64 + r)) * 2048 + j0 + cc);
    }
    __syncthreads();

    // AC = (Q+rw) @ K^T
    f32x4 sc[4];
#pragma unroll
    for (int fj = 0; fj < 4; ++fj) sc[fj] = zero4;
#pragma unroll
    for (int ks = 0; ks < 2; ++ks)
#pragma unroll
      for (int fj = 0; fj < 4; ++fj) {
        s16x8 bf = *(const s16x8*)&KtPt[fj * 16 + c16][ks * 32 + g * 8];
        sc[fj] = __builtin_amdgcn_mfma_f32_16x16x32_bf16(qw[ks], bf, sc[fj], 0, 0, 0);
      }

    // QR band producer, shift baked in: St[w][r - delta] (delta wave-uniform)
#pragma unroll
    for (int c2 = 0; c2 < 2; ++c2) {
      const int cfe = wv * 2 + c2;
      const bool du = (cfe >= cfthr);   // wave-uniform delta for this w-column
      const int w = cfe * 16 + c16;
#pragma unroll
      for (int rg = 0; rg < 4; ++rg) {
        f32x4 qr = zero4;
        qr = __builtin_amdgcn_mfma_f32_16x16x32_bf16(qr_a[rg][0], rbf[c2][0], qr, 0, 0, 0);
        qr = __builtin_amdgcn_mfma_f32_16x16x32_bf16(qr_a[rg][1], rbf[c2][1], qr, 0, 0, 0);
        const int B = rg * 16 + g * 4;  // output row base (even -> b32-aligned)
        if (!du) {
          *(unsigned*)&St[w][B] = pack2(qr[0], qr[1]);
          *(unsigned*)&St[w][B + 2] = pack2(qr[2], qr[3]);
        } else if (B == 0) {
          // rows r=0..3 -> r'=-1..2: drop r'=-1
          *(unsigned*)&St[w][0] = pack2(qr[1], qr[2]);
          St[w][2] = f2bf(qr[3]);
        } else {
          St[w][B - 1] = f2bf(qr[0]);
          *(unsigned*)&St[w][B] = pack2(qr[1], qr[2]);
          St[w][B + 2] = f2bf(qr[3]);
        }
      }
      // band row 64 -> St[w][63] (only when delta=1)
      if (du) {
        f32x4 q64o = zero4;
        q64o = __builtin_amdgcn_mfma_f32_16x16x32_bf16(q64[0], rbf[c2][0], q64o, 0, 0, 0);
        q64o = __builtin_amdgcn_mfma_f32_16x16x32_bf16(q64[1], rbf[c2][1], q64o, 0, 0, 0);
        if (g == 0) St[w][63] = f2bf(q64o[0]);
      }
    }
    __syncthreads();

    // gather BD: one base pointer + compile-time immediate offsets
    {
      const char* Sbase = (const char*)&St[0][0] +
                          ((c16 + 63) * 132 - (wv * 16 + g * 4) * 130 - 390);
#pragma unroll
      for (int fj = 0; fj < 4; ++fj)
#pragma unroll
        for (int reg = 0; reg < 4; ++reg)
          sc[fj][reg] += bf2f(*(const u16*)(Sbase + fj * 2112 + (3 - reg) * 130));
    }

    // online softmax
    float mt[4];
#pragma unroll
    for (int reg = 0; reg < 4; ++reg)
      mt[reg] = fmaxf(fmaxf(sc[0][reg], sc[1][reg]), fmaxf(sc[2][reg], sc[3][reg]));
#pragma unroll
    for (int off = 1; off < 16; off <<= 1)
#pragma unroll
      for (int reg = 0; reg < 4; ++reg)
        mt[reg] = fmaxf(mt[reg], __shfl_xor(mt[reg], off, 16));
    float al[4], rs[4];
#pragma unroll
    for (int reg = 0; reg < 4; ++reg) {
      float mn = fmaxf(m_prev[reg], mt[reg]);
      al[reg] = __builtin_amdgcn_exp2f((m_prev[reg] - mn) * KEXP);
      m_prev[reg] = mn;
      rs[reg] = 0.f;
    }
    // P tile into KtPt (Kt fully consumed before the post-QR barrier)
#pragma unroll
    for (int fj = 0; fj < 4; ++fj)
#pragma unroll
      for (int reg = 0; reg < 4; ++reg) {
        float p = __builtin_amdgcn_exp2f((sc[fj][reg] - m_prev[reg]) * KEXP);
        rs[reg] += p;
        KtPt[wv * 16 + g * 4 + reg][fj * 16 + c16] = f2bf(p);
      }
#pragma unroll
    for (int off = 1; off < 16; off <<= 1)
#pragma unroll
      for (int reg = 0; reg < 4; ++reg)
        rs[reg] += __shfl_xor(rs[reg], off, 16);
#pragma unroll
    for (int reg = 0; reg < 4; ++reg)
      l_sum[reg] = l_sum[reg] * al[reg] + rs[reg];
#pragma unroll
    for (int fd = 0; fd < 4; ++fd)
#pragma unroll
      for (int reg = 0; reg < 4; ++reg)
        o_acc[fd][reg] *= al[reg];

    // PV: O += P @ V   (P rows are same-wave; compiler inserts lgkmcnt)
#pragma unroll
    for (int ks = 0; ks < 2; ++ks) {
      s16x8 pa = *(const s16x8*)&KtPt[wv * 16 + c16][ks * 32 + g * 8];
#pragma unroll
      for (int fd = 0; fd < 4; ++fd) {
        s16x8 vb = *(const s16x8*)&Vt[fd * 16 + c16][ks * 32 + g * 8];
        o_acc[fd] = __builtin_amdgcn_mfma_f32_16x16x32_bf16(pa, vb, o_acc[fd], 0, 0, 0);
      }
    }
  }

#pragma unroll
  for (int reg = 0; reg < 4; ++reg) {
    float inv = 1.0f / l_sum[reg];
    int i = i0 + wv * 16 + g * 4 + reg;
    u16* dst = av + ((size_t)(i * 2 + b)) * 1024 + n * 64;
#pragma unroll
    for (int fd = 0; fd < 4; ++fd)
      dst[fd * 16 + c16] = f2bf(o_acc[fd][reg] * inv);
  }
}

// ---------------- LayerNorm over rows of tmp (= attn_out + h) ----------------
__global__ __launch_bounds__(256) void k_ln(const float* __restrict__ tmp,
                                            const float* __restrict__ gamma,
                                            const float* __restrict__ beta,
                                            float* __restrict__ out) {
  __shared__ float r1[4], r2[4];
  const int row = blockIdx.x, tid = threadIdx.x;
  const float* x = tmp + (size_t)row * 1024;
  float4 v = *(const float4*)(x + tid * 4);
  float s1 = v.x + v.y + v.z + v.w;
  float s2 = v.x * v.x + v.y * v.y + v.z * v.z + v.w * v.w;
#pragma unroll
  for (int off = 1; off < 64; off <<= 1) {
    s1 += __shfl_xor(s1, off, 64);
    s2 += __shfl_xor(s2, off, 64);
  }
  if ((tid & 63) == 0) { r1[tid >> 6] = s1; r2[tid >> 6] = s2; }
  __syncthreads();
  s1 = r1[0] + r1[1] + r1[2] + r1[3];
  s2 = r2[0] + r2[1] + r2[2] + r2[3];
  float mu = s1 * (1.f / 1024.f);
  float var = s2 * (1.f / 1024.f) - mu * mu;
  float rstd = rsqrtf(var + 1e-6f);
  float4 gm = *(const float4*)(gamma + tid * 4);
  float4 bt = *(const float4*)(beta + tid * 4);
  float4 o;
  o.x = (v.x - mu) * rstd * gm.x + bt.x;
  o.y = (v.y - mu) * rstd * gm.y + bt.y;
  o.z = (v.z - mu) * rstd * gm.z + bt.z;
  o.w = (v.w - mu) * rstd * gm.w + bt.w;
  *(float4*)(out + (size_t)row * 1024 + tid * 4) = o;
}

// ---------------- launch ----------------
extern "C" void kernel_launch(void* const* d_in, const int* in_sizes, int n_in,
                              void* d_out, int out_size, void* d_ws, size_t ws_size,
                              hipStream_t stream) {
  const float* h    = (const float*)d_in[0];
  const float* r    = (const float*)d_in[1];
  const float* rwb  = (const float*)d_in[2];
  const float* rrb  = (const float*)d_in[3];
  const float* Wqkv = (const float*)d_in[4];
  const float* Wr   = (const float*)d_in[5];
  const float* Wo   = (const float*)d_in[6];
  const float* gam  = (const float*)d_in[7];
  const float* bet  = (const float*)d_in[8];
  float* out = (float*)d_out;

  u16* hb     = (u16*)d_ws;                          // 4096*1024
  u16* Wqkv_t = hb + (size_t)4096 * 1024;            // 3072*1024
  u16* Wr_t   = Wqkv_t + (size_t)3072 * 1024;        // 1024*1024
  u16* Wo_t   = Wr_t + (size_t)1024 * 1024;          // 1024*1024
  u16* rb     = Wo_t + (size_t)1024 * 1024;          // 2048*1024
  u16* qkv    = rb + (size_t)2048 * 1024;            // 4096*3072
  u16* rk     = qkv + (size_t)4096 * 3072;           // 2048*1024
  u16* vT     = rk + (size_t)2048 * 1024;            // 2*16*64*2048
  u16* av     = vT + (size_t)2 * 16 * 64 * 2048;     // 4096*1024
  float* tmp  = (float*)(av + (size_t)4096 * 1024);  // 4096*1024 f32

  k_cvt<<<4096, 256, 0, stream>>>(h, hb, 4096 * 1024 / 4);
  k_cvt<<<2048, 256, 0, stream>>>(r, rb, 2048 * 1024 / 4);
  k_tcvt<<<dim3(48, 16), 256, 0, stream>>>(Wqkv, Wqkv_t, 1024, 3072);
  k_tcvt<<<dim3(16, 16), 256, 0, stream>>>(Wr, Wr_t, 1024, 1024);
  k_tcvt<<<dim3(16, 16), 256, 0, stream>>>(Wo, Wo_t, 1024, 1024);
  k_gemm_bt<0><<<dim3(32, 24), 256, 0, stream>>>(hb, Wqkv_t, qkv, nullptr, nullptr,
                                                 4096, 3072, 1024);
  k_gemm_bt<0><<<dim3(16, 8), 256, 0, stream>>>(rb, Wr_t, rk, nullptr, nullptr,
                                                2048, 1024, 1024);
  k_vt<<<dim3(32, 32), 256, 0, stream>>>(qkv, vT);
  k_attn<<<1024, 256, 0, stream>>>(qkv, rk, vT, rwb, rrb, av);
  k_gemm_bt<1><<<dim3(32, 8), 256, 0, stream>>>(av, Wo_t, nullptr, tmp, h,
                                                4096, 1024, 1024);
  k_ln<<<4096, 256, 0, stream>>>(tmp, gam, bet, out);
}

// Round 6
// 279.282 us; speedup vs baseline: 1.3199x; 1.2798x over previous
//
#include <hip/hip_runtime.h>
#include <hip/hip_bf16.h>

typedef unsigned short u16;
typedef __attribute__((ext_vector_type(8))) short s16x8;
typedef __attribute__((ext_vector_type(8))) unsigned short u16x8;
typedef __attribute__((ext_vector_type(4))) float f32x4;

#define SEQ 2048
#define KEXP 0.18033688011112042f  /* 0.125 * log2(e) */

__device__ __forceinline__ float bf2f(u16 x) {
  union { unsigned u; float f; } c; c.u = ((unsigned)x) << 16; return c.f;
}
// hardware bf16 convert (v_cvt_pk_bf16_f32 on gfx950)
__device__ __forceinline__ u16 f2bf(float f) {
  __hip_bfloat16 h = __float2bfloat16(f);
  return __builtin_bit_cast(u16, h);
}
__device__ __forceinline__ unsigned pack2(float a, float b) {
  return (unsigned)f2bf(a) | ((unsigned)f2bf(b) << 16);
}

// ---------------- fp32 -> bf16 flat convert ----------------
__global__ __launch_bounds__(256) void k_cvt(const float* __restrict__ src,
                                             u16* __restrict__ dst, int n4) {
  int i = blockIdx.x * 256 + threadIdx.x;
  if (i >= n4) return;
  float4 v = ((const float4*)src)[i];
  ((ushort4*)dst)[i] = make_ushort4(f2bf(v.x), f2bf(v.y), f2bf(v.z), f2bf(v.w));
}

// ---------------- fp32 [R][C] -> bf16 [C][R] transpose-convert ----------------
__global__ __launch_bounds__(256) void k_tcvt(const float* __restrict__ src,
                                              u16* __restrict__ dst, int R, int C) {
  __shared__ u16 T[64][72];
  int r0 = blockIdx.y * 64, c0 = blockIdx.x * 64;
  int tid = threadIdx.x;
#pragma unroll
  for (int p = 0; p < 4; ++p) {
    int f = p * 256 + tid;            // float4 id within 64x64 tile
    int r = f >> 4, cc = (f & 15) * 4;
    float4 v = *(const float4*)(src + (size_t)(r0 + r) * C + c0 + cc);
    T[r][cc + 0] = f2bf(v.x); T[r][cc + 1] = f2bf(v.y);
    T[r][cc + 2] = f2bf(v.z); T[r][cc + 3] = f2bf(v.w);
  }
  __syncthreads();
#pragma unroll
  for (int p = 0; p < 2; ++p) {
    int f = p * 256 + tid;            // u16x8 chunk id
    int c = f >> 3, rr = (f & 7) * 8;
    u16x8 v;
#pragma unroll
    for (int e = 0; e < 8; ++e) v[e] = T[rr + e][c];
    *(u16x8*)(dst + (size_t)(c0 + c) * R + r0 + rr) = v;
  }
}

// ---------------- C[M,N] = A[M,K] @ Bt[N,K]^T  (bf16 in, bf16 or f32+res out) ----
template <int RES>
__global__ __launch_bounds__(256) void k_gemm_bt(const u16* __restrict__ A,
                                                 const u16* __restrict__ Bt,
                                                 u16* __restrict__ Cb,
                                                 float* __restrict__ Cf,
                                                 const float* __restrict__ res,
                                                 int M, int N, int K) {
  __shared__ u16 As[128 * 72];
  __shared__ u16 Bs[128 * 72];
  const int tid = threadIdx.x;
  const int l = tid & 63, wv = tid >> 6;
  const int g = l >> 4, c16 = l & 15;
  const int m0 = blockIdx.x * 128, n0 = blockIdx.y * 128;
  const int wr = (wv >> 1) * 64, wc = (wv & 1) * 64;
  f32x4 acc[4][4] = {};
  for (int k0 = 0; k0 < K; k0 += 64) {
    __syncthreads();
    // 128 rows x 64 k = 1024 16B-chunks per matrix; 256 threads -> 4 iters
#pragma unroll
    for (int p = 0; p < 4; ++p) {
      int f = p * 256 + tid;
      int row = f >> 3, kb = (f & 7) * 8;
      u16x8 va = *(const u16x8*)(A + (size_t)(m0 + row) * K + k0 + kb);
      u16x8 vb = *(const u16x8*)(Bt + (size_t)(n0 + row) * K + k0 + kb);
      *(u16x8*)&As[row * 72 + kb] = va;
      *(u16x8*)&Bs[row * 72 + kb] = vb;
    }
    __syncthreads();
#pragma unroll
    for (int ks = 0; ks < 2; ++ks) {
      s16x8 af[4], bf[4];
#pragma unroll
      for (int fr = 0; fr < 4; ++fr)
        af[fr] = *(const s16x8*)&As[(wr + fr * 16 + c16) * 72 + ks * 32 + g * 8];
#pragma unroll
      for (int fc = 0; fc < 4; ++fc)
        bf[fc] = *(const s16x8*)&Bs[(wc + fc * 16 + c16) * 72 + ks * 32 + g * 8];
#pragma unroll
      for (int fr = 0; fr < 4; ++fr)
#pragma unroll
        for (int fc = 0; fc < 4; ++fc)
          acc[fr][fc] = __builtin_amdgcn_mfma_f32_16x16x32_bf16(af[fr], bf[fc],
                                                                acc[fr][fc], 0, 0, 0);
    }
  }
#pragma unroll
  for (int fr = 0; fr < 4; ++fr)
#pragma unroll
    for (int fc = 0; fc < 4; ++fc)
#pragma unroll
      for (int reg = 0; reg < 4; ++reg) {
        int row = m0 + wr + fr * 16 + g * 4 + reg;
        int col = n0 + wc + fc * 16 + c16;
        float v = acc[fr][fc][reg];
        if (RES) Cf[(size_t)row * N + col] = v + res[(size_t)row * N + col];
        else     Cb[(size_t)row * N + col] = f2bf(v);
      }
}

// ---------------- build V^T [b][n][d][j] from qkv ----------------
__global__ __launch_bounds__(256) void k_vt(const u16* __restrict__ qkv,
                                            u16* __restrict__ vT) {
  __shared__ u16 T[64][72];
  const int tid = threadIdx.x;
  const int j0 = blockIdx.x * 64;
  const int n = blockIdx.y & 15, b = blockIdx.y >> 4;
#pragma unroll
  for (int p = 0; p < 2; ++p) {
    int f = p * 256 + tid;
    int r = f >> 3, cc = (f & 7) * 8;
    *(u16x8*)&T[r][cc] =
        *(const u16x8*)(qkv + ((size_t)((j0 + r) * 2 + b)) * 3072 + 2048 + n * 64 + cc);
  }
  __syncthreads();
#pragma unroll
  for (int p = 0; p < 2; ++p) {
    int f = p * 256 + tid;
    int d = f >> 3, jc = (f & 7) * 8;
    u16x8 v;
#pragma unroll
    for (int e = 0; e < 8; ++e) v[e] = T[jc + e][d];
    *(u16x8*)(vT + ((size_t)((b * 16 + n) * 64 + d)) * 2048 + j0 + jc) = v;
  }
}

// ---------------- fused rel-attention (flash-style, KVBLK=128) ----------------
// Registers (arch+acc ~150+) cap residency at 2 waves/SIMD regardless of LDS
// (R3/R5 both ~26% occupancy) -> spend LDS freely (78.6KB, 2 blocks/CU) and
// maximize per-wave ILP: 2 barriers/iter, prefetch K/V/rk into regs during PV.
__global__ __launch_bounds__(256) void k_attn(const u16* __restrict__ qkv,
                                              const u16* __restrict__ rk,
                                              const u16* __restrict__ vT,
                                              const float* __restrict__ rwb,
                                              const float* __restrict__ rrb,
                                              u16* __restrict__ av) {
  __shared__ u16 Kt[128][72];   // K tile [j][d]
  __shared__ u16 Vt[64][136];   // V^T tile [d][j]
  __shared__ u16 St[192][66];   // shifted band S^T[w][ii] = QR[ii+delta(w)][w]
  __shared__ u16 Pt[64][136];   // P (probs)

  const int tid = threadIdx.x;
  const int l = tid & 63, wv = tid >> 6;
  const int g = l >> 4, c16 = l & 15;
  // XCD-aware swizzle: 4 consecutive bn per XCD -> K/V/rk L2-resident
  const int s = blockIdx.x;
  const int y = (s & 7) + 8 * (s >> 8);  // bn
  const int x = (s >> 3) & 31;           // i-tile
  const int i0 = x * 64;
  const int n = y & 15, b = y >> 4;
  const f32x4 zero4 = {0.f, 0.f, 0.f, 0.f};
  const s16x8 zero8 = {0, 0, 0, 0, 0, 0, 0, 0};

  // ---- register-staged Q fragments (loop-invariant) ----
  s16x8 qw[2];  // AC A-frag (Q + r_w_bias)
  {
    int i = i0 + wv * 16 + c16;
    const u16* src = qkv + ((size_t)(i * 2 + b)) * 3072 + n * 64;
#pragma unroll
    for (int ks = 0; ks < 2; ++ks) {
      int d0 = ks * 32 + g * 8;
      u16x8 raw = *(const u16x8*)(src + d0);
      u16x8 wq;
#pragma unroll
      for (int e = 0; e < 8; ++e)
        wq[e] = f2bf(bf2f(raw[e]) + rwb[n * 64 + d0 + e]);
      qw[ks] = __builtin_bit_cast(s16x8, wq);
    }
  }
  s16x8 qr_a[4][2];  // QR producer A-frags (Q + r_r_bias)
#pragma unroll
  for (int rg = 0; rg < 4; ++rg) {
    int i = i0 + rg * 16 + c16;
    const u16* src = qkv + ((size_t)(i * 2 + b)) * 3072 + n * 64;
#pragma unroll
    for (int ks = 0; ks < 2; ++ks) {
      int d0 = ks * 32 + g * 8;
      u16x8 raw = *(const u16x8*)(src + d0);
      u16x8 wq;
#pragma unroll
      for (int e = 0; e < 8; ++e)
        wq[e] = f2bf(bf2f(raw[e]) + rrb[n * 64 + d0 + e]);
      qr_a[rg][ks] = __builtin_bit_cast(s16x8, wq);
    }
  }
  s16x8 q64[2];  // band row 64 in lane c16==0 only
  {
    bool valid = (c16 == 0) && (i0 + 64 < SEQ);
#pragma unroll
    for (int ks = 0; ks < 2; ++ks) q64[ks] = zero8;
    if (valid) {
      const u16* src = qkv + ((size_t)((i0 + 64) * 2 + b)) * 3072 + n * 64;
#pragma unroll
      for (int ks = 0; ks < 2; ++ks) {
        int d0 = ks * 32 + g * 8;
        u16x8 raw = *(const u16x8*)(src + d0);
        u16x8 wq;
#pragma unroll
        for (int e = 0; e < 8; ++e)
          wq[e] = f2bf(bf2f(raw[e]) + rrb[n * 64 + d0 + e]);
        q64[ks] = __builtin_bit_cast(s16x8, wq);
      }
    }
  }

  // prefetch registers (T14: issued during previous iteration's PV)
  u16x8 kpre[4], vpre[4];
  s16x8 rpre[3][2];
  auto issue_loads = [&](int j0n) {
#pragma unroll
    for (int p = 0; p < 4; ++p) {
      int f = p * 256 + tid;
      kpre[p] = *(const u16x8*)(qkv + ((size_t)((j0n + (f >> 3)) * 2 + b)) * 3072 +
                                1024 + n * 64 + (f & 7) * 8);
    }
#pragma unroll
    for (int p = 0; p < 4; ++p) {
      int f = p * 256 + tid;
      vpre[p] = *(const u16x8*)(vT + ((size_t)((b * 16 + n) * 64 + (f >> 4))) * 2048 +
                                j0n + (f & 15) * 8);
    }
#pragma unroll
    for (int c3 = 0; c3 < 3; ++c3) {
      int w = (wv * 3 + c3) * 16 + c16;
      int u = j0n - i0 - 63 + w;
      int c = (u <= 0) ? (u + (SEQ - 1)) : (u - 2);
      const u16* p = rk + (size_t)(c < 0 ? 0 : c) * 1024 + n * 64;
      rpre[c3][0] = *(const s16x8*)(p + g * 8);
      rpre[c3][1] = *(const s16x8*)(p + 32 + g * 8);
      if (c < 0) { rpre[c3][0] = zero8; rpre[c3][1] = zero8; }
    }
  };

  float m_prev[4], l_sum[4];
  f32x4 o_acc[4];
#pragma unroll
  for (int r = 0; r < 4; ++r) { m_prev[r] = -1e30f; l_sum[r] = 0.f; o_acc[r] = zero4; }

  issue_loads(0);

  for (int it = 0; it < 16; ++it) {
    const int j0 = it * 128;
    const int cfthr = (64 + i0 - j0) >> 4;  // delta(w)= (w>=thr), thr%64==0
    __syncthreads();  // prev-iter St/Pt/Kt/Vt reads complete

    // ds-write staged K/V (vmcnt hidden under previous PV)
#pragma unroll
    for (int p = 0; p < 4; ++p) {
      int f = p * 256 + tid;
      *(u16x8*)&Kt[f >> 3][(f & 7) * 8] = kpre[p];
    }
#pragma unroll
    for (int p = 0; p < 4; ++p) {
      int f = p * 256 + tid;
      *(u16x8*)&Vt[f >> 4][(f & 15) * 8] = vpre[p];
    }

    // QR band producer (registers only) runs while stage-writes drain
#pragma unroll
    for (int c3 = 0; c3 < 3; ++c3) {
      const int cfe = wv * 3 + c3;
      const bool du = (cfe >= cfthr);  // wave-uniform per w-column
      const int w = cfe * 16 + c16;
#pragma unroll
      for (int rg = 0; rg < 4; ++rg) {
        f32x4 qr = zero4;
        qr = __builtin_amdgcn_mfma_f32_16x16x32_bf16(qr_a[rg][0], rpre[c3][0], qr, 0, 0, 0);
        qr = __builtin_amdgcn_mfma_f32_16x16x32_bf16(qr_a[rg][1], rpre[c3][1], qr, 0, 0, 0);
        const int B = rg * 16 + g * 4;
        if (!du) {
          *(unsigned*)&St[w][B] = pack2(qr[0], qr[1]);
          *(unsigned*)&St[w][B + 2] = pack2(qr[2], qr[3]);
        } else if (B == 0) {
          *(unsigned*)&St[w][0] = pack2(qr[1], qr[2]);
          St[w][2] = f2bf(qr[3]);
        } else {
          St[w][B - 1] = f2bf(qr[0]);
          *(unsigned*)&St[w][B] = pack2(qr[1], qr[2]);
          St[w][B + 2] = f2bf(qr[3]);
        }
      }
      if (du) {  // band row 64 -> St[w][63]
        f32x4 q64o = zero4;
        q64o = __builtin_amdgcn_mfma_f32_16x16x32_bf16(q64[0], rpre[c3][0], q64o, 0, 0, 0);
        q64o = __builtin_amdgcn_mfma_f32_16x16x32_bf16(q64[1], rpre[c3][1], q64o, 0, 0, 0);
        if (g == 0) St[w][63] = f2bf(q64o[0]);
      }
    }
    __syncthreads();  // Kt, Vt, St visible

    // AC = (Q+rw) @ K^T  (128 cols)
    f32x4 sc[8];
#pragma unroll
    for (int fj = 0; fj < 8; ++fj) sc[fj] = zero4;
#pragma unroll
    for (int ks = 0; ks < 2; ++ks)
#pragma unroll
      for (int fj = 0; fj < 8; ++fj) {
        s16x8 bf = *(const s16x8*)&Kt[fj * 16 + c16][ks * 32 + g * 8];
        sc[fj] = __builtin_amdgcn_mfma_f32_16x16x32_bf16(qw[ks], bf, sc[fj], 0, 0, 0);
      }

    // gather BD: one base pointer + compile-time immediate offsets
    {
      const char* Sbase = (const char*)&St[0][0] +
                          (c16 * 132 - (wv * 16 + g * 4) * 130 + 7926);
#pragma unroll
      for (int fj = 0; fj < 8; ++fj)
#pragma unroll
        for (int reg = 0; reg < 4; ++reg)
          sc[fj][reg] += bf2f(*(const u16*)(Sbase + fj * 2112 + (3 - reg) * 130));
    }

    // online softmax (one chain per 128 cols)
    float mt[4];
#pragma unroll
    for (int reg = 0; reg < 4; ++reg) {
      mt[reg] = sc[0][reg];
#pragma unroll
      for (int fj = 1; fj < 8; ++fj) mt[reg] = fmaxf(mt[reg], sc[fj][reg]);
    }
#pragma unroll
    for (int off = 1; off < 16; off <<= 1)
#pragma unroll
      for (int reg = 0; reg < 4; ++reg)
        mt[reg] = fmaxf(mt[reg], __shfl_xor(mt[reg], off, 16));
    float al[4], rs[4];
#pragma unroll
    for (int reg = 0; reg < 4; ++reg) {
      float mn = fmaxf(m_prev[reg], mt[reg]);
      al[reg] = __builtin_amdgcn_exp2f((m_prev[reg] - mn) * KEXP);
      m_prev[reg] = mn;
      rs[reg] = 0.f;
    }
#pragma unroll
    for (int fj = 0; fj < 8; ++fj)
#pragma unroll
      for (int reg = 0; reg < 4; ++reg) {
        float p = __builtin_amdgcn_exp2f((sc[fj][reg] - m_prev[reg]) * KEXP);
        rs[reg] += p;
        Pt[wv * 16 + g * 4 + reg][fj * 16 + c16] = f2bf(p);
      }
#pragma unroll
    for (int off = 1; off < 16; off <<= 1)
#pragma unroll
      for (int reg = 0; reg < 4; ++reg)
        rs[reg] += __shfl_xor(rs[reg], off, 16);
#pragma unroll
    for (int reg = 0; reg < 4; ++reg)
      l_sum[reg] = l_sum[reg] * al[reg] + rs[reg];
#pragma unroll
    for (int fd = 0; fd < 4; ++fd)
#pragma unroll
      for (int reg = 0; reg < 4; ++reg)
        o_acc[fd][reg] *= al[reg];

    // prefetch next tile's K/V/rk while PV runs
    if (it < 15) issue_loads(j0 + 128);

    // PV: O += P @ V  (P rows are this wave's own strip; lgkm handled)
#pragma unroll
    for (int ks = 0; ks < 4; ++ks) {
      s16x8 pa = *(const s16x8*)&Pt[wv * 16 + c16][ks * 32 + g * 8];
#pragma unroll
      for (int fd = 0; fd < 4; ++fd) {
        s16x8 vb = *(const s16x8*)&Vt[fd * 16 + c16][ks * 32 + g * 8];
        o_acc[fd] = __builtin_amdgcn_mfma_f32_16x16x32_bf16(pa, vb, o_acc[fd], 0, 0, 0);
      }
    }
  }

#pragma unroll
  for (int reg = 0; reg < 4; ++reg) {
    float inv = 1.0f / l_sum[reg];
    int i = i0 + wv * 16 + g * 4 + reg;
    u16* dst = av + ((size_t)(i * 2 + b)) * 1024 + n * 64;
#pragma unroll
    for (int fd = 0; fd < 4; ++fd)
      dst[fd * 16 + c16] = f2bf(o_acc[fd][reg] * inv);
  }
}

// ---------------- LayerNorm over rows of tmp (= attn_out + h) ----------------
__global__ __launch_bounds__(256) void k_ln(const float* __restrict__ tmp,
                                            const float* __restrict__ gamma,
                                            const float* __restrict__ beta,
                                            float* __restrict__ out) {
  __shared__ float r1[4], r2[4];
  const int row = blockIdx.x, tid = threadIdx.x;
  const float* x = tmp + (size_t)row * 1024;
  float4 v = *(const float4*)(x + tid * 4);
  float s1 = v.x + v.y + v.z + v.w;
  float s2 = v.x * v.x + v.y * v.y + v.z * v.z + v.w * v.w;
#pragma unroll
  for (int off = 1; off < 64; off <<= 1) {
    s1 += __shfl_xor(s1, off, 64);
    s2 += __shfl_xor(s2, off, 64);
  }
  if ((tid & 63) == 0) { r1[tid >> 6] = s1; r2[tid >> 6] = s2; }
  __syncthreads();
  s1 = r1[0] + r1[1] + r1[2] + r1[3];
  s2 = r2[0] + r2[1] + r2[2] + r2[3];
  float mu = s1 * (1.f / 1024.f);
  float var = s2 * (1.f / 1024.f) - mu * mu;
  float rstd = rsqrtf(var + 1e-6f);
  float4 gm = *(const float4*)(gamma + tid * 4);
  float4 bt = *(const float4*)(beta + tid * 4);
  float4 o;
  o.x = (v.x - mu) * rstd * gm.x + bt.x;
  o.y = (v.y - mu) * rstd * gm.y + bt.y;
  o.z = (v.z - mu) * rstd * gm.z + bt.z;
  o.w = (v.w - mu) * rstd * gm.w + bt.w;
  *(float4*)(out + (size_t)row * 1024 + tid * 4) = o;
}

// ---------------- launch ----------------
extern "C" void kernel_launch(void* const* d_in, const int* in_sizes, int n_in,
                              void* d_out, int out_size, void* d_ws, size_t ws_size,
                              hipStream_t stream) {
  const float* h    = (const float*)d_in[0];
  const float* r    = (const float*)d_in[1];
  const float* rwb  = (const float*)d_in[2];
  const float* rrb  = (const float*)d_in[3];
  const float* Wqkv = (const float*)d_in[4];
  const float* Wr   = (const float*)d_in[5];
  const float* Wo   = (const float*)d_in[6];
  const float* gam  = (const float*)d_in[7];
  const float* bet  = (const float*)d_in[8];
  float* out = (float*)d_out;

  u16* hb     = (u16*)d_ws;                          // 4096*1024
  u16* Wqkv_t = hb + (size_t)4096 * 1024;            // 3072*1024
  u16* Wr_t   = Wqkv_t + (size_t)3072 * 1024;        // 1024*1024
  u16* Wo_t   = Wr_t + (size_t)1024 * 1024;          // 1024*1024
  u16* rb     = Wo_t + (size_t)1024 * 1024;          // 2048*1024
  u16* qkv    = rb + (size_t)2048 * 1024;            // 4096*3072
  u16* rk     = qkv + (size_t)4096 * 3072;           // 2048*1024
  u16* vT     = rk + (size_t)2048 * 1024;            // 2*16*64*2048
  u16* av     = vT + (size_t)2 * 16 * 64 * 2048;     // 4096*1024
  float* tmp  = (float*)(av + (size_t)4096 * 1024);  // 4096*1024 f32

  k_cvt<<<4096, 256, 0, stream>>>(h, hb, 4096 * 1024 / 4);
  k_cvt<<<2048, 256, 0, stream>>>(r, rb, 2048 * 1024 / 4);
  k_tcvt<<<dim3(48, 16), 256, 0, stream>>>(Wqkv, Wqkv_t, 1024, 3072);
  k_tcvt<<<dim3(16, 16), 256, 0, stream>>>(Wr, Wr_t, 1024, 1024);
  k_tcvt<<<dim3(16, 16), 256, 0, stream>>>(Wo, Wo_t, 1024, 1024);
  k_gemm_bt<0><<<dim3(32, 24), 256, 0, stream>>>(hb, Wqkv_t, qkv, nullptr, nullptr,
                                                 4096, 3072, 1024);
  k_gemm_bt<0><<<dim3(16, 8), 256, 0, stream>>>(rb, Wr_t, rk, nullptr, nullptr,
                                                2048, 1024, 1024);
  k_vt<<<dim3(32, 32), 256, 0, stream>>>(qkv, vT);
  k_attn<<<1024, 256, 0, stream>>>(qkv, rk, vT, rwb, rrb, av);
  k_gemm_bt<1><<<dim3(32, 8), 256, 0, stream>>>(av, Wo_t, nullptr, tmp, h,
                                                4096, 1024, 1024);
  k_ln<<<4096, 256, 0, stream>>>(tmp, gam, bet, out);
}